// Round 1
// 343.277 us; speedup vs baseline: 1.0922x; 1.0922x over previous
//
#include <hip/hip_runtime.h>
#include <stdint.h>

typedef short short8 __attribute__((ext_vector_type(8)));
typedef float f32x4 __attribute__((ext_vector_type(4)));
typedef unsigned short ushort4v __attribute__((ext_vector_type(4)));
typedef unsigned int uint4v __attribute__((ext_vector_type(4)));
typedef unsigned long long u64;

#if __has_builtin(__builtin_amdgcn_exp2f)
#define EXP2(x) __builtin_amdgcn_exp2f(x)
#else
#define EXP2(x) exp2f(x)
#endif

__device__ __forceinline__ unsigned perm_hi16(unsigned hi, unsigned lo) {
#if __has_builtin(__builtin_amdgcn_perm)
  return __builtin_amdgcn_perm(hi, lo, 0x07060302u);
#else
  return (hi & 0xffff0000u) | (lo >> 16);
#endif
}

// f32 -> bf16 round-to-nearest-even
__device__ __forceinline__ unsigned short f2bf(float f) {
  union { float f; unsigned u; } v; v.f = f;
  unsigned r = v.u + 0x7fffu + ((v.u >> 16) & 1u);
  return (unsigned short)(r >> 16);
}

// packed f32x2 -> bf16x2 (lo -> bits[15:0], hi -> bits[31:16])
__device__ __forceinline__ unsigned cvt_pk_bf16(float lo, float hi) {
  unsigned r;
  asm("v_cvt_pk_bf16_f32 %0, %1, %2" : "=v"(r) : "v"(lo), "v"(hi));
  return r;
}

// async global->LDS, 16B per lane; lds dst is wave-uniform base + lane*16
__device__ __forceinline__ void gld_lds16(const void* g, void* l) {
  __builtin_amdgcn_global_load_lds((const __attribute__((address_space(1))) void*)g,
                                   (__attribute__((address_space(3))) void*)l, 16, 0, 0);
}

// ---------------- mask -> per-lane-ownership bit pack ----------------
// u64 word w = (b*1024+q)*16 + ktb*2 + gh  (gh = g>>1).
// Bit j of word: glo=j>>5, nt=(j&31)>>2, r=j&3, g=gh*2+glo,
//   k (within 128-block) = nt*16 + g*4 + r.
// flash lane(fr,g) loads word (qrow*16 + ktb*2 + (g>>1)), takes the 32-bit half
// selected by (g&1); bit (nt*4+r) masks its score S[q=fr][k=nt*16+g*4+r].
__global__ void mask_pack(const int* __restrict__ mask, u64* __restrict__ bits) {
  const int tid = blockIdx.x * 256 + threadIdx.x;
  const int w = tid >> 6, j = tid & 63;
  const int gh = w & 1, ktb = (w >> 1) & 7, bq = w >> 4;
  const int nt = (j >> 2) & 7, r = j & 3, g = gh * 2 + (j >> 5);
  const int k = nt * 16 + g * 4 + r;
  const int v = mask[(size_t)bq * 1024 + ktb * 128 + k];
  const u64 b = __ballot(v != 0);
  if (j == 0) bits[w] = b;
}

// ---------------- RoPE + cast to bf16 (query,key) ----------------
__global__ void rope_kernel(const float* __restrict__ q, const float* __restrict__ k,
                            const float* __restrict__ cs, const float* __restrict__ sn,
                            unsigned short* __restrict__ qo, unsigned short* __restrict__ ko) {
  const int idx = blockIdx.x * 256 + threadIdx.x;
  const int p   = idx & 7;
  const int bth = idx >> 3;
  const int t   = (bth >> 4) & 1023;
  const size_t base = (size_t)bth * 64;
  const int dd0 = p * 4;

  const float4 x0 = *(const float4*)(q + base + dd0);
  const float4 x1 = *(const float4*)(q + base + dd0 + 32);
  const float4 y0 = *(const float4*)(k + base + dd0);
  const float4 y1 = *(const float4*)(k + base + dd0 + 32);
  const float4 c0 = *(const float4*)(cs + t * 64 + dd0);
  const float4 c1 = *(const float4*)(cs + t * 64 + dd0 + 32);
  const float4 s0 = *(const float4*)(sn + t * 64 + dd0);
  const float4 s1 = *(const float4*)(sn + t * 64 + dd0 + 32);

  ushort4v qlo, qhi, klo, khi;
  qlo[0]=f2bf(x0.x*c0.x - x1.x*s0.x); qlo[1]=f2bf(x0.y*c0.y - x1.y*s0.y);
  qlo[2]=f2bf(x0.z*c0.z - x1.z*s0.z); qlo[3]=f2bf(x0.w*c0.w - x1.w*s0.w);
  qhi[0]=f2bf(x1.x*c1.x + x0.x*s1.x); qhi[1]=f2bf(x1.y*c1.y + x0.y*s1.y);
  qhi[2]=f2bf(x1.z*c1.z + x0.z*s1.z); qhi[3]=f2bf(x1.w*c1.w + x0.w*s1.w);
  klo[0]=f2bf(y0.x*c0.x - y1.x*s0.x); klo[1]=f2bf(y0.y*c0.y - y1.y*s0.y);
  klo[2]=f2bf(y0.z*c0.z - y1.z*s0.z); klo[3]=f2bf(y0.w*c0.w - y1.w*s0.w);
  khi[0]=f2bf(y1.x*c1.x + y0.x*s1.x); khi[1]=f2bf(y1.y*c1.y + y0.y*s1.y);
  khi[2]=f2bf(y1.z*c1.z + y0.z*s1.z); khi[3]=f2bf(y1.w*c1.w + y0.w*s1.w);

  *(ushort4v*)(qo + base + dd0)      = qlo;
  *(ushort4v*)(qo + base + dd0 + 32) = qhi;
  *(ushort4v*)(ko + base + dd0)      = klo;
  *(ushort4v*)(ko + base + dd0 + 32) = khi;
}

// ---------------- plain f32 -> bf16 cast ----------------
__global__ void cast_kernel(const float* __restrict__ src, unsigned short* __restrict__ dst, int n4) {
  const int i = blockIdx.x * 256 + threadIdx.x;
  if (i < n4) {
    const float4 v = *(const float4*)(src + (size_t)i * 4);
    ushort4v o;
    o[0]=f2bf(v.x); o[1]=f2bf(v.y); o[2]=f2bf(v.z); o[3]=f2bf(v.w);
    *(ushort4v*)(dst + (size_t)i * 4) = o;
  }
}

// ---------------- fused 4x weight cast ----------------
__global__ void cast4_kernel(const float* __restrict__ s0, const float* __restrict__ s1,
                             const float* __restrict__ s2, const float* __restrict__ s3,
                             unsigned short* __restrict__ d0, unsigned short* __restrict__ d1,
                             unsigned short* __restrict__ d2, unsigned short* __restrict__ d3) {
  const int m = blockIdx.y;
  const float* src = (m == 0) ? s0 : (m == 1) ? s1 : (m == 2) ? s2 : s3;
  unsigned short* dst = (m == 0) ? d0 : (m == 1) ? d1 : (m == 2) ? d2 : d3;
  const int i = blockIdx.x * 256 + threadIdx.x;
  const float4 v = *(const float4*)(src + (size_t)i * 4);
  ushort4v o;
  o[0]=f2bf(v.x); o[1]=f2bf(v.y); o[2]=f2bf(v.z); o[3]=f2bf(v.w);
  *(ushort4v*)(dst + (size_t)i * 4) = o;
}

// ---------------- bf16 GEMM, C[m,n] = (sum_k A[m,k]*B[n,k] + bias[n]) * scale ----------------
// MODE 0: f32 row-major. MODE 1: bf16 (b,h,t,d). MODE 2: bf16 (b,h,d,t') with t'
// k-permuted within 128-blocks to match the register-resident P fragments of
// flash_attn's swapped QK^T:  k' = (nt&3)*32 + g*8 + (nt>>2)*4 + r
// where nt=(k>>4)&7, g=(k>>2)&3, r=k&3.
template <int MODE>
__global__ __launch_bounds__(256, 2) void gemm_bt(
    const unsigned short* __restrict__ A, const unsigned short* __restrict__ Bw,
    const float* __restrict__ bias, void* __restrict__ C, float scale) {
  constexpr int K = 1024, N = 1024;
  const int tid = threadIdx.x;
  const int wave = tid >> 6, lane = tid & 63;
  const int m0 = blockIdx.x * 128, n0 = blockIdx.y * 128;
  __shared__ unsigned short Asm[128 * 64];
  __shared__ unsigned short Bsm[128 * 64];
  f32x4 acc[4][4] = {};
  const int wr = (wave >> 1) * 64, wc = (wave & 1) * 64;
  const int ld_row = lane >> 3;
  const int ld_col = ((lane & 7) ^ ld_row) * 8;       // swizzled fetch chunk
  const int fr = lane & 15, g = lane >> 4;
  const int fr7 = fr & 7;

  for (int k0 = 0; k0 < K; k0 += 64) {
#pragma unroll
    for (int j = 0; j < 4; ++j) {
      const int c = j * 4 + wave;
      gld_lds16(A  + (size_t)(m0 + 8 * c + ld_row) * K + k0 + ld_col, &Asm[c * 512]);
      gld_lds16(Bw + (size_t)(n0 + 8 * c + ld_row) * K + k0 + ld_col, &Bsm[c * 512]);
    }
    __syncthreads();
#pragma unroll
    for (int ks = 0; ks < 2; ++ks) {
      const int ch = ((ks * 4 + g) ^ fr7) * 8;        // swizzled fragment chunk
      short8 af[4], bf[4];
#pragma unroll
      for (int i = 0; i < 4; ++i)
        af[i] = *(const short8*)&Asm[(wr + i * 16 + fr) * 64 + ch];
#pragma unroll
      for (int i = 0; i < 4; ++i)
        bf[i] = *(const short8*)&Bsm[(wc + i * 16 + fr) * 64 + ch];
#pragma unroll
      for (int i = 0; i < 4; ++i)
#pragma unroll
        for (int j = 0; j < 4; ++j)
          acc[i][j] = __builtin_amdgcn_mfma_f32_16x16x32_bf16(af[i], bf[j], acc[i][j], 0, 0, 0);
    }
    __syncthreads();
  }

#pragma unroll
  for (int i = 0; i < 4; ++i) {
    const int row_base = m0 + wr + i * 16 + g * 4;
#pragma unroll
    for (int j = 0; j < 4; ++j) {
      const int col = n0 + wc + j * 16 + fr;
      const float bval = bias[col];
      if (MODE == 0) {
        float* Co = (float*)C;
#pragma unroll
        for (int r = 0; r < 4; ++r)
          Co[(size_t)(row_base + r) * N + col] = (acc[i][j][r] + bval) * scale;
      } else if (MODE == 1) {
        unsigned short* Co = (unsigned short*)C;
        const int h_i = col >> 6, dd = col & 63;
#pragma unroll
        for (int r = 0; r < 4; ++r) {
          const int row = row_base + r;
          const int b_i = row >> 10, t_i = row & 1023;
          Co[((size_t)(b_i * 16 + h_i) * 1024 + t_i) * 64 + dd] = f2bf((acc[i][j][r] + bval) * scale);
        }
      } else {
        unsigned short* Co = (unsigned short*)C;
        const int h_i = col >> 6, dd = col & 63;
#pragma unroll
        for (int r = 0; r < 4; ++r) {
          const int row = row_base + r;
          const int b_i = row >> 10, t_i = row & 1023;
          const int kk = t_i & 127;
          const int kp = ((kk >> 4) & 3) * 32 + ((kk >> 2) & 3) * 8 + ((kk >> 6) & 1) * 4 + (kk & 3);
          Co[((size_t)(b_i * 16 + h_i) * 64 + dd) * 1024 + (t_i & ~127) + kp] =
              f2bf((acc[i][j][r] + bval) * scale);
        }
      }
    }
  }
}

// ---------------- flash attention (no-max softmax, register-resident P) ----------------
// Swapped QK^T: s = mfma(K, Q) -> lane(fr,g) holds S[q=fr][k=nt*16+g*4+r] for
// nt in [0,8), r in [0,4) -- 32 scores, all for one q-row, all in its own g-subset.
// With V stored under k' = (nt&3)*32 + g*8 + (nt>>2)*4 + r, the exp'd scores ARE
// the PV A-fragments: P never touches LDS, no cross-lane ops, no overlay barrier.
// Qp pre-scaled by 0.125*log2(e) in its GEMM epilogue -> p = exp2(s_acc) directly.
__global__ __launch_bounds__(256, 2) void flash_attn(
    const unsigned short* __restrict__ Qp, const unsigned short* __restrict__ Kp,
    const unsigned short* __restrict__ Vp, const u64* __restrict__ mbits,
    unsigned short* __restrict__ O) {
  const int bh = blockIdx.x & 127, b_i = bh >> 4, h_i = bh & 15;
  const int q0 = (blockIdx.x >> 7) * 128;
  const int tid = threadIdx.x, wave = tid >> 6, lane = tid & 63;
  const unsigned short* Qb = Qp + (size_t)bh * 65536;
  const unsigned short* Kb = Kp + (size_t)bh * 65536;
  const unsigned short* Vb = Vp + (size_t)bh * 65536;
  const u64* mb = mbits + (size_t)b_i * 16384;

  __shared__ unsigned short smem[16384];
  unsigned short* Vsm = smem;                      // [64][128] swizzled
  unsigned short* Ksm = smem + 8192;               // [128][64] swizzled

  const int fr = lane & 15, g = lane >> 4, fr7 = fr & 7;
  const int qw = q0 + wave * 32;

  short8 qf[2][2];
#pragma unroll
  for (int mt = 0; mt < 2; ++mt)
#pragma unroll
    for (int ks = 0; ks < 2; ++ks)
      qf[mt][ks] = *(const short8*)&Qb[(size_t)(qw + mt * 16 + fr) * 64 + ks * 32 + g * 8];

  f32x4 o_acc[2][4] = {};
  float l_run[2] = {0.0f, 0.0f};

  const int kld_row = lane >> 3;
  const int kld_col = ((lane & 7) ^ kld_row) * 8;                  // K swizzled fetch
  const int vld_row = lane >> 4;
  const int vld_r7w = 4 * (wave & 1) + vld_row;                    // (row&7) for V staging
  const int vld_col = ((lane & 15) ^ vld_r7w) * 8;                 // V swizzled fetch

  for (int kt = 0; kt < 1024; kt += 128) {
#pragma unroll
    for (int j = 0; j < 4; ++j) {
      const int c = j * 4 + wave;
      gld_lds16(Kb + (size_t)(kt + 8 * c + kld_row) * 64 + kld_col, &Ksm[c * 512]);
      gld_lds16(Vb + (size_t)(4 * c + vld_row) * 1024 + kt + vld_col, &Vsm[c * 512]);
    }
    __syncthreads();

    // S^T = K Q^T  (per wave: 128 k-rows x 32 q-cols)
    f32x4 s_acc[2][8] = {};
#pragma unroll
    for (int ks = 0; ks < 2; ++ks) {
      const int ch = ((ks * 4 + g) ^ fr7) * 8;
      short8 kf[8];
#pragma unroll
      for (int nt = 0; nt < 8; ++nt)
        kf[nt] = *(const short8*)&Ksm[(nt * 16 + fr) * 64 + ch];
      __builtin_amdgcn_s_setprio(1);
#pragma unroll
      for (int mt = 0; mt < 2; ++mt)
#pragma unroll
        for (int nt = 0; nt < 8; ++nt)
          s_acc[mt][nt] = __builtin_amdgcn_mfma_f32_16x16x32_bf16(kf[nt], qf[mt][ks], s_acc[mt][nt], 0, 0, 0);
      __builtin_amdgcn_s_setprio(0);
    }

    // softmax: exp2 + mask + pack to bf16 PV-fragments, all in registers.
    // pf[mt][ks2] elem e: e<4 -> (nt=ks2, r=e); e>=4 -> (nt=ks2+4, r=e-4).
    short8 pf[2][4];
#pragma unroll
    for (int mt = 0; mt < 2; ++mt) {
      const u64 w = mb[(size_t)(qw + mt * 16 + fr) * 16 + (kt >> 7) * 2 + (g >> 1)];
      const unsigned bits = (unsigned)(w >> ((g & 1) * 32));
      float lp = l_run[mt];
#pragma unroll
      for (int ks2 = 0; ks2 < 4; ++ks2) {
        float e[8];
#pragma unroll
        for (int r = 0; r < 4; ++r) {
          float a = EXP2(s_acc[mt][ks2][r]);
          a = (bits & (1u << (ks2 * 4 + r))) ? 0.0f : a;
          float b2 = EXP2(s_acc[mt][ks2 + 4][r]);
          b2 = (bits & (1u << (16 + ks2 * 4 + r))) ? 0.0f : b2;
          e[r] = a; e[4 + r] = b2;
          lp += a + b2;
        }
        uint4v pk;
        pk[0] = cvt_pk_bf16(e[0], e[1]);
        pk[1] = cvt_pk_bf16(e[2], e[3]);
        pk[2] = cvt_pk_bf16(e[4], e[5]);
        pk[3] = cvt_pk_bf16(e[6], e[7]);
        union { uint4v u; short8 s; } cv; cv.u = pk;
        pf[mt][ks2] = cv.s;
      }
      l_run[mt] = lp;
    }

    // O += P V   (V fragments loaded once, shared across both q-tiles)
#pragma unroll
    for (int ks2 = 0; ks2 < 4; ++ks2) {
      const int cc = (ks2 * 4 + g) ^ fr7;
      short8 vf[4];
#pragma unroll
      for (int dt = 0; dt < 4; ++dt)
        vf[dt] = *(const short8*)&Vsm[(dt * 16 + fr) * 128 + cc * 8];
      __builtin_amdgcn_s_setprio(1);
#pragma unroll
      for (int mt = 0; mt < 2; ++mt)
#pragma unroll
        for (int dt = 0; dt < 4; ++dt)
          o_acc[mt][dt] = __builtin_amdgcn_mfma_f32_16x16x32_bf16(pf[mt][ks2], vf[dt], o_acc[mt][dt], 0, 0, 0);
      __builtin_amdgcn_s_setprio(0);
    }
    __syncthreads();
  }

  // l lives per-lane for q-row fr (split across g); reduce over g, redistribute
  // to the o_acc row owner (row g*4+r), normalize, write O as (b,t,f) bf16.
#pragma unroll
  for (int mt = 0; mt < 2; ++mt) {
    float red = l_run[mt];
    red += __shfl_xor(red, 16);
    red += __shfl_xor(red, 32);
#pragma unroll
    for (int r = 0; r < 4; ++r) {
      const float lv = __shfl(red, g * 4 + r);
      const float inv_l = 1.0f / lv;
      const int qrow = qw + mt * 16 + g * 4 + r;
#pragma unroll
      for (int dt = 0; dt < 4; ++dt) {
        const int dcol = dt * 16 + fr;
        O[((size_t)(b_i * 1024 + qrow)) * 1024 + h_i * 64 + dcol] = f2bf(o_acc[mt][dt][r] * inv_l);
      }
    }
  }
}

extern "C" void kernel_launch(void* const* d_in, const int* in_sizes, int n_in,
                              void* d_out, int out_size, void* d_ws, size_t ws_size,
                              hipStream_t stream) {
  const float* query = (const float*)d_in[0];
  const float* key   = (const float*)d_in[1];
  const float* value = (const float*)d_in[2];
  const float* cosb  = (const float*)d_in[3];
  const float* sinb  = (const float*)d_in[4];
  const int*   mask  = (const int*)d_in[5];
  const float* Wq = (const float*)d_in[6];
  const float* bq = (const float*)d_in[7];
  const float* Wk = (const float*)d_in[8];
  const float* bk = (const float*)d_in[9];
  const float* Wv = (const float*)d_in[10];
  const float* bv = (const float*)d_in[11];
  const float* Wo = (const float*)d_in[12];
  const float* bo = (const float*)d_in[13];
  (void)in_sizes; (void)n_in; (void)out_size; (void)ws_size;

  char* ws = (char*)d_ws;
  const size_t MB = 1024 * 1024;
  unsigned short* q_in = (unsigned short*)(ws);
  unsigned short* k_in = (unsigned short*)(ws + 16 * MB);
  unsigned short* v_bf = (unsigned short*)(ws + 32 * MB);
  unsigned short* Qp   = (unsigned short*)(ws + 48 * MB);
  unsigned short* Kp   = (unsigned short*)(ws + 64 * MB);
  unsigned short* Vp   = (unsigned short*)(ws + 80 * MB);
  unsigned short* Wqb  = (unsigned short*)(ws + 96 * MB);
  unsigned short* Wkb  = (unsigned short*)(ws + 98 * MB);
  unsigned short* Wvb  = (unsigned short*)(ws + 100 * MB);
  unsigned short* Wob  = (unsigned short*)(ws + 102 * MB);
  u64*            mbits= (u64*)(ws + 104 * MB);
  unsigned short* attn = q_in;

  mask_pack<<<32768, 256, 0, stream>>>(mask, mbits);
  rope_kernel<<<4096, 256, 0, stream>>>(query, key, cosb, sinb, q_in, k_in);
  cast_kernel<<<8192, 256, 0, stream>>>(value, v_bf, 2097152);
  cast4_kernel<<<dim3(1024, 4), 256, 0, stream>>>(Wq, Wk, Wv, Wo, Wqb, Wkb, Wvb, Wob);

  dim3 g(64, 8), blk(256);
  gemm_bt<1><<<g, blk, 0, stream>>>(q_in, Wqb, bq, Qp, 0.18033688f);  // 0.125*log2(e) folded
  gemm_bt<1><<<g, blk, 0, stream>>>(k_in, Wkb, bk, Kp, 1.0f);
  gemm_bt<2><<<g, blk, 0, stream>>>(v_bf, Wvb, bv, Vp, 1.0f);
  flash_attn<<<1024, blk, 0, stream>>>(Qp, Kp, Vp, mbits, attn);
  gemm_bt<0><<<g, blk, 0, stream>>>(attn, Wob, bo, d_out, 1.0f);
}